// Round 1
// baseline (520.343 us; speedup 1.0000x reference)
//
#include <hip/hip_runtime.h>
#include <math.h>

#define SEQ    2048
#define NBATCH 4
#define NTOK   8192
#define EMB    768
#define DFF    3072
#define NH     8
#define HD     96
#define QSEG   6291456   // 32 pairs * 2048 * 96

typedef float            f32x4  __attribute__((ext_vector_type(4)));
typedef __bf16           bf16x8 __attribute__((ext_vector_type(8)));
typedef unsigned short   u16;
typedef u16              u16x8  __attribute__((ext_vector_type(8)));
typedef u16              u16x4  __attribute__((ext_vector_type(4)));

__device__ __forceinline__ u16 f2bf(float f) {
  union { float f; unsigned u; } v; v.f = f;
  unsigned r = v.u + 0x7FFFu + ((v.u >> 16) & 1u);
  return (u16)(r >> 16);
}
__device__ __forceinline__ bf16x8 asbf(u16x8 v) { return __builtin_bit_cast(bf16x8, v); }

__device__ __forceinline__ void gload16(const void* g, void* l) {
  __builtin_amdgcn_global_load_lds((const __attribute__((address_space(1))) unsigned*)g,
                                   (__attribute__((address_space(3))) unsigned*)l, 16, 0, 0);
}

// ---------------------------------------------------------------------------
// Generic fp32 [R][C] -> bf16 transposed [C][R] (weights -> B^T bf16)
// ---------------------------------------------------------------------------
__global__ __launch_bounds__(256)
void transpose_cvt(const float* __restrict__ in, u16* __restrict__ out, int R, int C) {
  __shared__ float tile[32][33];
  const int c0 = blockIdx.x * 32, r0 = blockIdx.y * 32;
  const int tr = threadIdx.x >> 5, tc = threadIdx.x & 31;
#pragma unroll
  for (int i = 0; i < 4; ++i)
    tile[tr + 8 * i][tc] = in[(size_t)(r0 + tr + 8 * i) * C + c0 + tc];
  __syncthreads();
#pragma unroll
  for (int i = 0; i < 4; ++i)
    out[(size_t)(c0 + tr + 8 * i) * R + r0 + tc] = f2bf(tile[tc][tr + 8 * i]);
}

__global__ __launch_bounds__(256)
void concat_bias(const float* __restrict__ bq, const float* __restrict__ bk,
                 const float* __restrict__ bv, float* __restrict__ out) {
  int i = blockIdx.x * 256 + threadIdx.x;
  if (i < 2304) {
    const float* s = (i < 768) ? bq : ((i < 1536) ? bk : bv);
    out[i] = s[i % 768];
  }
}

// ---------------------------------------------------------------------------
// LayerNorm: fp32 [rows][768] -> bf16 [rows][768]; one wave per row
// ---------------------------------------------------------------------------
__global__ __launch_bounds__(256)
void ln_k(const float* __restrict__ x, const float* __restrict__ g,
          const float* __restrict__ b, u16* __restrict__ y) {
  const int row = blockIdx.x * 4 + (threadIdx.x >> 6);
  const int l = threadIdx.x & 63;
  const float* xr = x + (size_t)row * EMB;
  f32x4 v[3];
#pragma unroll
  for (int i = 0; i < 3; ++i) v[i] = *(const f32x4*)(xr + (l + 64 * i) * 4);
  float s = 0.f;
#pragma unroll
  for (int i = 0; i < 3; ++i)
#pragma unroll
    for (int j = 0; j < 4; ++j) s += v[i][j];
#pragma unroll
  for (int m = 32; m; m >>= 1) s += __shfl_xor(s, m, 64);
  const float mu = s * (1.0f / EMB);
  float q = 0.f;
#pragma unroll
  for (int i = 0; i < 3; ++i)
#pragma unroll
    for (int j = 0; j < 4; ++j) { float d = v[i][j] - mu; q += d * d; }
#pragma unroll
  for (int m = 32; m; m >>= 1) q += __shfl_xor(q, m, 64);
  const float rstd = rsqrtf(q * (1.0f / EMB) + 1e-5f);
#pragma unroll
  for (int i = 0; i < 3; ++i) {
    const int c0 = (l + 64 * i) * 4;
    f32x4 gv = *(const f32x4*)(g + c0);
    f32x4 bv = *(const f32x4*)(b + c0);
    u16x4 o;
#pragma unroll
    for (int j = 0; j < 4; ++j) o[j] = f2bf((v[i][j] - mu) * rstd * gv[j] + bv[j]);
    *(u16x4*)(y + (size_t)row * EMB + c0) = o;
  }
}

// ---------------------------------------------------------------------------
// GEMM: C[M][N] = A[M][K](bf16) @ B^T[N][K](bf16) + epilogue
// EPI 0: +bias, scatter bf16 to qkv head layout   (outp = qkv u16 base)
// EPI 1: +bias +resid -> fp32                      (outp = fp32)
// EPI 2: +bias, exact GELU -> bf16                 (outp = u16)
// EPI 3: +bias +resid -> fp32                      (outp = fp32)
// 128x128 tile, BK=32, 4 waves, 4x4 16x16x32 frags per wave.
// ---------------------------------------------------------------------------
template <int EPI>
__global__ __launch_bounds__(256, 3)
void gemm_k(const u16* __restrict__ A, const u16* __restrict__ BT,
            const float* __restrict__ bias, const float* __restrict__ resid,
            void* __restrict__ outp, int M, int N, int K, int nbn) {
  __shared__ __align__(16) u16 sA[128 * 32];
  __shared__ __align__(16) u16 sB[128 * 32];
  const int t = threadIdx.x;
  const int w = t >> 6, l = t & 63;
  const int wr = w >> 1, wc = w & 1;
  const int lr = l & 15, lg = l >> 4;
  const int bm = blockIdx.x / nbn, bn = blockIdx.x % nbn;
  const int m0 = bm << 7, n0 = bn << 7;

  // staging: thread t covers LDS bytes [t*16, t*16+16) of each 4KB half
  const int r0 = t >> 2;                 // LDS row (first half), row+64 second
  const int cL = t & 3;                  // LDS chunk (8 elems)
  const int cG0 = cL ^ ((r0 >> 1) & 3);  // swizzled global chunk
  const int cG1 = cL ^ (((r0 + 64) >> 1) & 3);
  const u16* gA0 = A + (size_t)(m0 + r0) * K + cG0 * 8;
  const u16* gA1 = A + (size_t)(m0 + r0 + 64) * K + cG1 * 8;
  const u16* gB0 = BT + (size_t)(n0 + r0) * K + cG0 * 8;
  const u16* gB1 = BT + (size_t)(n0 + r0 + 64) * K + cG1 * 8;
  u16* lA0 = sA + t * 8;
  u16* lA1 = sA + 2048 + t * 8;
  u16* lB0 = sB + t * 8;
  u16* lB1 = sB + 2048 + t * 8;

  f32x4 acc[4][4] = {};
  const int swz = (lr >> 1) & 3;  // read-side swizzle selector

  for (int kt = 0; kt < K; kt += 32) {
    __syncthreads();
    gload16(gA0 + kt, lA0);
    gload16(gA1 + kt, lA1);
    gload16(gB0 + kt, lB0);
    gload16(gB1 + kt, lB1);
    __syncthreads();
    bf16x8 af[4], bfr[4];
#pragma unroll
    for (int mf = 0; mf < 4; ++mf) {
      int r = wr * 64 + mf * 16 + lr;
      af[mf] = asbf(*(const u16x8*)(sA + r * 32 + ((lg ^ swz) * 8)));
    }
#pragma unroll
    for (int nf = 0; nf < 4; ++nf) {
      int r = wc * 64 + nf * 16 + lr;
      bfr[nf] = asbf(*(const u16x8*)(sB + r * 32 + ((lg ^ swz) * 8)));
    }
#pragma unroll
    for (int mf = 0; mf < 4; ++mf)
#pragma unroll
      for (int nf = 0; nf < 4; ++nf)
        acc[mf][nf] = __builtin_amdgcn_mfma_f32_16x16x32_bf16(af[mf], bfr[nf], acc[mf][nf], 0, 0, 0);
  }

  // epilogue: C/D layout col=lane&15, row=(lane>>4)*4+j  [m89/m91 verified]
#pragma unroll
  for (int nf = 0; nf < 4; ++nf) {
    const int col = n0 + wc * 64 + nf * 16 + lr;
    const float bcol = bias[col];
    if (EPI == 0) {
      const int which = col / 768;
      const int cm = col - which * 768;
      const int h = cm / 96;
      const int d = cm - h * 96;
      u16* qb = (u16*)outp + (size_t)which * QSEG;
#pragma unroll
      for (int mf = 0; mf < 4; ++mf)
#pragma unroll
        for (int j = 0; j < 4; ++j) {
          const int row = m0 + wr * 64 + mf * 16 + lg * 4 + j;
          const int b = row >> 11, tok = row & 2047;
          qb[((size_t)((b * NH + h) * SEQ + tok)) * HD + d] = f2bf(acc[mf][nf][j] + bcol);
        }
    } else {
#pragma unroll
      for (int mf = 0; mf < 4; ++mf)
#pragma unroll
        for (int j = 0; j < 4; ++j) {
          const int row = m0 + wr * 64 + mf * 16 + lg * 4 + j;
          const float v = acc[mf][nf][j] + bcol;
          const size_t off = (size_t)row * N + col;
          if (EPI == 1 || EPI == 3) {
            ((float*)outp)[off] = v + resid[off];
          } else {  // EPI == 2, exact GELU
            ((u16*)outp)[off] = f2bf(0.5f * v * (1.0f + erff(v * 0.70710678f)));
          }
        }
    }
  }
}

// ---------------------------------------------------------------------------
// Flash attention. qkv: bf16, q/k/v segments of [32 pairs][2048][96].
// Block = 4 waves; wave owns 16 Q rows (Q-tile 64); K-tile 64; 32 kt iters.
// softmax is UNSCALED (faithful to ref); 1/sqrt(768) folded into final O.
// Output obuf: bf16 [b][tok][h*96+d] = [8192][768].
// ---------------------------------------------------------------------------
__global__ __launch_bounds__(256, 2)
void attn_k(const u16* __restrict__ qkv, u16* __restrict__ obuf) {
  __shared__ __align__(16) u16 sK[64 * 120];   // rows=k-rows, 120-elem stride
  __shared__ __align__(16) u16 sVt[96 * 72];   // rows=d, cols=k, 72-elem stride
  __shared__ __align__(16) u16 sP[4][16 * 72]; // per-wave P[16][64], 72 stride
  const int p = blockIdx.y;   // (b,h) pair
  const int qt = blockIdx.x;  // q tile
  const int t = threadIdx.x;
  const int w = t >> 6, l = t & 63;
  const int lr = l & 15, lg = l >> 4;
  const u16* qb = qkv + (size_t)p * SEQ * HD;
  const u16* kb = qb + QSEG;
  const u16* vb = qb + 2 * (size_t)QSEG;
  const int q0 = qt * 64 + w * 16;

  bf16x8 aq[3];
#pragma unroll
  for (int kb3 = 0; kb3 < 3; ++kb3)
    aq[kb3] = asbf(*(const u16x8*)(qb + (size_t)(q0 + lr) * HD + kb3 * 32 + lg * 8));

  f32x4 accO[6] = {};
  float mrow[4] = {-1e30f, -1e30f, -1e30f, -1e30f};
  float lrow[4] = {0.f, 0.f, 0.f, 0.f};

  for (int kt = 0; kt < 32; ++kt) {
    __syncthreads();
    const u16* kbase = kb + (size_t)(kt * 64) * HD;
    const u16* vbase = vb + (size_t)(kt * 64) * HD;
#pragma unroll
    for (int j = 0; j < 3; ++j) {
      const int c0 = (w + j * 4) * 8;
      u16x8 kv = *(const u16x8*)(kbase + (size_t)l * HD + c0);
      *(u16x8*)(&sK[l * 120 + c0]) = kv;
      u16x8 vv = *(const u16x8*)(vbase + (size_t)l * HD + c0);
#pragma unroll
      for (int i = 0; i < 8; ++i) sVt[(c0 + i) * 72 + l] = vv[i];
    }
    __syncthreads();

    // S = Q @ K^T  (rows: lg*4+j, cols: nf*16+lr)
    f32x4 s4[4] = {};
#pragma unroll
    for (int nf = 0; nf < 4; ++nf)
#pragma unroll
      for (int kb3 = 0; kb3 < 3; ++kb3) {
        bf16x8 bk_ = asbf(*(const u16x8*)(&sK[(nf * 16 + lr) * 120 + kb3 * 32 + lg * 8]));
        s4[nf] = __builtin_amdgcn_mfma_f32_16x16x32_bf16(aq[kb3], bk_, s4[nf], 0, 0, 0);
      }

    // online softmax (row reductions across 16-lane groups)
    float tmax[4];
#pragma unroll
    for (int j = 0; j < 4; ++j) {
      tmax[j] = fmaxf(fmaxf(s4[0][j], s4[1][j]), fmaxf(s4[2][j], s4[3][j]));
#pragma unroll
      for (int m = 8; m; m >>= 1) tmax[j] = fmaxf(tmax[j], __shfl_xor(tmax[j], m, 64));
    }
    float alpha[4];
#pragma unroll
    for (int j = 0; j < 4; ++j) {
      const float mn = fmaxf(mrow[j], tmax[j]);
      alpha[j] = __expf(mrow[j] - mn);
      mrow[j] = mn;
    }
    float psum[4] = {0.f, 0.f, 0.f, 0.f};
#pragma unroll
    for (int nf = 0; nf < 4; ++nf)
#pragma unroll
      for (int j = 0; j < 4; ++j) {
        const float pv = __expf(s4[nf][j] - mrow[j]);
        psum[j] += pv;
        sP[w][(lg * 4 + j) * 72 + nf * 16 + lr] = f2bf(pv);
      }
#pragma unroll
    for (int j = 0; j < 4; ++j) {
#pragma unroll
      for (int m = 8; m; m >>= 1) psum[j] += __shfl_xor(psum[j], m, 64);
      lrow[j] = lrow[j] * alpha[j] + psum[j];
    }
#pragma unroll
    for (int nf2 = 0; nf2 < 6; ++nf2)
#pragma unroll
      for (int j = 0; j < 4; ++j) accO[nf2][j] *= alpha[j];

    asm volatile("s_waitcnt lgkmcnt(0)" ::: "memory");

    // O += P @ V  (A = P[16][64] from sP, B = V via transposed sVt)
#pragma unroll
    for (int kf = 0; kf < 2; ++kf) {
      bf16x8 ap = asbf(*(const u16x8*)(&sP[w][lr * 72 + kf * 32 + lg * 8]));
#pragma unroll
      for (int nf2 = 0; nf2 < 6; ++nf2) {
        bf16x8 bv_ = asbf(*(const u16x8*)(&sVt[(nf2 * 16 + lr) * 72 + kf * 32 + lg * 8]));
        accO[nf2] = __builtin_amdgcn_mfma_f32_16x16x32_bf16(ap, bv_, accO[nf2], 0, 0, 0);
      }
    }
  }

  // epilogue: O / (l * sqrt(768)), scatter to [b][tok][h*96+d]
  const int b = p >> 3, h = p & 7;
  float sc[4];
#pragma unroll
  for (int j = 0; j < 4; ++j) sc[j] = 0.03608439182435161f / lrow[j];
#pragma unroll
  for (int nf2 = 0; nf2 < 6; ++nf2)
#pragma unroll
    for (int j = 0; j < 4; ++j) {
      const int tok = q0 + lg * 4 + j;
      obuf[(size_t)(b * SEQ + tok) * EMB + h * HD + nf2 * 16 + lr] = f2bf(accO[nf2][j] * sc[j]);
    }
}

// ---------------------------------------------------------------------------
extern "C" void kernel_launch(void* const* d_in, const int* in_sizes, int n_in,
                              void* d_out, int out_size, void* d_ws, size_t ws_size,
                              hipStream_t stream) {
  const float* x    = (const float*)d_in[0];
  const float* ln1g = (const float*)d_in[1];
  const float* ln1b = (const float*)d_in[2];
  const float* wq   = (const float*)d_in[3];
  const float* bq   = (const float*)d_in[4];
  const float* wk   = (const float*)d_in[5];
  const float* bk   = (const float*)d_in[6];
  const float* wv   = (const float*)d_in[7];
  const float* bv   = (const float*)d_in[8];
  const float* wo   = (const float*)d_in[9];
  const float* bo   = (const float*)d_in[10];
  const float* ln2g = (const float*)d_in[11];
  const float* ln2b = (const float*)d_in[12];
  const float* w1   = (const float*)d_in[13];
  const float* b1   = (const float*)d_in[14];
  const float* w2   = (const float*)d_in[15];
  const float* b2   = (const float*)d_in[16];
  float* out = (float*)d_out;

  char* ws = (char*)d_ws;
  u16* wqkvT  = (u16*)ws;   ws += (size_t)2304 * 768 * 2;
  u16* woT    = (u16*)ws;   ws += (size_t)768 * 768 * 2;
  u16* w1T    = (u16*)ws;   ws += (size_t)3072 * 768 * 2;
  u16* w2T    = (u16*)ws;   ws += (size_t)768 * 3072 * 2;
  float* bqkv = (float*)ws; ws += (size_t)2304 * 4;
  u16* bufA   = (u16*)ws;   ws += (size_t)NTOK * EMB * 2;   // y -> o -> z
  u16* bigbuf = (u16*)ws;   ws += (size_t)NTOK * DFF * 2;   // qkv -> ffn hidden
  float* x1   = (float*)ws; ws += (size_t)NTOK * EMB * 4;

  // weights -> bf16 B^T
  transpose_cvt<<<dim3(24, 24), 256, 0, stream>>>(wq, wqkvT, 768, 768);
  transpose_cvt<<<dim3(24, 24), 256, 0, stream>>>(wk, wqkvT + 768 * 768, 768, 768);
  transpose_cvt<<<dim3(24, 24), 256, 0, stream>>>(wv, wqkvT + 2 * 768 * 768, 768, 768);
  transpose_cvt<<<dim3(24, 24), 256, 0, stream>>>(wo, woT, 768, 768);
  transpose_cvt<<<dim3(96, 24), 256, 0, stream>>>(w1, w1T, 768, 3072);
  transpose_cvt<<<dim3(24, 96), 256, 0, stream>>>(w2, w2T, 3072, 768);
  concat_bias<<<9, 256, 0, stream>>>(bq, bk, bv, bqkv);

  // LN1 -> y (bf16)
  ln_k<<<NTOK / 4, 256, 0, stream>>>(x, ln1g, ln1b, bufA);
  // QKV projection, scatter to head layout
  gemm_k<0><<<64 * 18, 256, 0, stream>>>(bufA, wqkvT, bqkv, nullptr, bigbuf,
                                         NTOK, 2304, 768, 18);
  // attention -> o (bf16, token-major), reuses bufA
  attn_k<<<dim3(32, 32), 256, 0, stream>>>(bigbuf, bufA);
  // O projection + residual -> x1 (fp32)
  gemm_k<1><<<64 * 6, 256, 0, stream>>>(bufA, woT, bo, x, x1, NTOK, 768, 768, 6);
  // LN2 -> z (bf16)
  ln_k<<<NTOK / 4, 256, 0, stream>>>(x1, ln2g, ln2b, bufA);
  // FFN1 + GELU -> hidden (bf16)
  gemm_k<2><<<64 * 24, 256, 0, stream>>>(bufA, w1T, b1, nullptr, bigbuf,
                                         NTOK, 3072, 768, 24);
  // FFN2 + residual -> out (fp32)
  gemm_k<3><<<64 * 6, 256, 0, stream>>>(bigbuf, w2T, b2, x1, out, NTOK, 768, 3072, 6);
}

// Round 2
// 487.800 us; speedup vs baseline: 1.0667x; 1.0667x over previous
//
#include <hip/hip_runtime.h>
#include <math.h>

#define SEQ    2048
#define NBATCH 4
#define NTOK   8192
#define EMB    768
#define DFF    3072
#define NH     8
#define HD     96
#define QSEG   6291456   // 32 pairs * 2048 * 96

typedef float            f32x4  __attribute__((ext_vector_type(4)));
typedef __bf16           bf16x8 __attribute__((ext_vector_type(8)));
typedef unsigned short   u16;
typedef u16              u16x8  __attribute__((ext_vector_type(8)));
typedef u16              u16x4  __attribute__((ext_vector_type(4)));

__device__ __forceinline__ u16 f2bf(float f) {
  union { float f; unsigned u; } v; v.f = f;
  unsigned r = v.u + 0x7FFFu + ((v.u >> 16) & 1u);
  return (u16)(r >> 16);
}
__device__ __forceinline__ bf16x8 asbf(u16x8 v) { return __builtin_bit_cast(bf16x8, v); }

__device__ __forceinline__ void gload16(const void* g, void* l) {
  __builtin_amdgcn_global_load_lds((const __attribute__((address_space(1))) unsigned*)g,
                                   (__attribute__((address_space(3))) unsigned*)l, 16, 0, 0);
}

// ---------------------------------------------------------------------------
// Generic fp32 [R][C] -> bf16 transposed [C][R] (weights -> B^T bf16)
// ---------------------------------------------------------------------------
__global__ __launch_bounds__(256)
void transpose_cvt(const float* __restrict__ in, u16* __restrict__ out, int R, int C) {
  __shared__ float tile[32][33];
  const int c0 = blockIdx.x * 32, r0 = blockIdx.y * 32;
  const int tr = threadIdx.x >> 5, tc = threadIdx.x & 31;
#pragma unroll
  for (int i = 0; i < 4; ++i)
    tile[tr + 8 * i][tc] = in[(size_t)(r0 + tr + 8 * i) * C + c0 + tc];
  __syncthreads();
#pragma unroll
  for (int i = 0; i < 4; ++i)
    out[(size_t)(c0 + tr + 8 * i) * R + r0 + tc] = f2bf(tile[tc][tr + 8 * i]);
}

__global__ __launch_bounds__(256)
void concat_bias(const float* __restrict__ bq, const float* __restrict__ bk,
                 const float* __restrict__ bv, float* __restrict__ out) {
  int i = blockIdx.x * 256 + threadIdx.x;
  if (i < 2304) {
    const float* s = (i < 768) ? bq : ((i < 1536) ? bk : bv);
    out[i] = s[i % 768];
  }
}

// ---------------------------------------------------------------------------
// LayerNorm: fp32 [rows][768] -> bf16 [rows][768]; one wave per row
// ---------------------------------------------------------------------------
__global__ __launch_bounds__(256)
void ln_k(const float* __restrict__ x, const float* __restrict__ g,
          const float* __restrict__ b, u16* __restrict__ y) {
  const int row = blockIdx.x * 4 + (threadIdx.x >> 6);
  const int l = threadIdx.x & 63;
  const float* xr = x + (size_t)row * EMB;
  f32x4 v[3];
#pragma unroll
  for (int i = 0; i < 3; ++i) v[i] = *(const f32x4*)(xr + (l + 64 * i) * 4);
  float s = 0.f;
#pragma unroll
  for (int i = 0; i < 3; ++i)
#pragma unroll
    for (int j = 0; j < 4; ++j) s += v[i][j];
#pragma unroll
  for (int m = 32; m; m >>= 1) s += __shfl_xor(s, m, 64);
  const float mu = s * (1.0f / EMB);
  float q = 0.f;
#pragma unroll
  for (int i = 0; i < 3; ++i)
#pragma unroll
    for (int j = 0; j < 4; ++j) { float d = v[i][j] - mu; q += d * d; }
#pragma unroll
  for (int m = 32; m; m >>= 1) q += __shfl_xor(q, m, 64);
  const float rstd = rsqrtf(q * (1.0f / EMB) + 1e-5f);
#pragma unroll
  for (int i = 0; i < 3; ++i) {
    const int c0 = (l + 64 * i) * 4;
    f32x4 gv = *(const f32x4*)(g + c0);
    f32x4 bv = *(const f32x4*)(b + c0);
    u16x4 o;
#pragma unroll
    for (int j = 0; j < 4; ++j) o[j] = f2bf((v[i][j] - mu) * rstd * gv[j] + bv[j]);
    *(u16x4*)(y + (size_t)row * EMB + c0) = o;
  }
}

// ---------------------------------------------------------------------------
// GEMM: C[M][N] = A[M][K](bf16) @ B^T[N][K](bf16) + epilogue
// EPI 0: +bias, scatter bf16 to qkv layout (Q,K: [p][tok][d]; V: [p][d][tok])
// EPI 1: +bias +resid -> fp32
// EPI 2: +bias, exact GELU -> bf16
// EPI 3: +bias +resid -> fp32
// 128x128 tile, BK=32, 4 waves, 4x4 16x16x32 frags per wave. XCD-swizzled grid.
// ---------------------------------------------------------------------------
template <int EPI>
__global__ __launch_bounds__(256, 3)
void gemm_k(const u16* __restrict__ A, const u16* __restrict__ BT,
            const float* __restrict__ bias, const float* __restrict__ resid,
            void* __restrict__ outp, int M, int N, int K, int nbn) {
  __shared__ __align__(16) u16 sA[128 * 32];
  __shared__ __align__(16) u16 sB[128 * 32];
  const int t = threadIdx.x;
  const int w = t >> 6, l = t & 63;
  const int wr = w >> 1, wc = w & 1;
  const int lr = l & 15, lg = l >> 4;
  // XCD chunk swizzle (all our grids are divisible by 8)
  const int cpx = gridDim.x >> 3;
  const int bid = (blockIdx.x & 7) * cpx + (blockIdx.x >> 3);
  const int bm = bid / nbn, bn = bid % nbn;
  const int m0 = bm << 7, n0 = bn << 7;

  // staging: thread t covers LDS bytes [t*16, t*16+16) of each 4KB half
  const int r0 = t >> 2;                 // LDS row (first half), row+64 second
  const int cL = t & 3;                  // LDS chunk (8 elems)
  const int cG0 = cL ^ ((r0 >> 1) & 3);  // swizzled global chunk
  const int cG1 = cL ^ (((r0 + 64) >> 1) & 3);
  const u16* gA0 = A + (size_t)(m0 + r0) * K + cG0 * 8;
  const u16* gA1 = A + (size_t)(m0 + r0 + 64) * K + cG1 * 8;
  const u16* gB0 = BT + (size_t)(n0 + r0) * K + cG0 * 8;
  const u16* gB1 = BT + (size_t)(n0 + r0 + 64) * K + cG1 * 8;
  u16* lA0 = sA + t * 8;
  u16* lA1 = sA + 2048 + t * 8;
  u16* lB0 = sB + t * 8;
  u16* lB1 = sB + 2048 + t * 8;

  f32x4 acc[4][4] = {};
  const int swz = (lr >> 1) & 3;  // read-side swizzle selector

  for (int kt = 0; kt < K; kt += 32) {
    __syncthreads();
    gload16(gA0 + kt, lA0);
    gload16(gA1 + kt, lA1);
    gload16(gB0 + kt, lB0);
    gload16(gB1 + kt, lB1);
    __syncthreads();
    bf16x8 af[4], bfr[4];
#pragma unroll
    for (int mf = 0; mf < 4; ++mf) {
      int r = wr * 64 + mf * 16 + lr;
      af[mf] = asbf(*(const u16x8*)(sA + r * 32 + ((lg ^ swz) * 8)));
    }
#pragma unroll
    for (int nf = 0; nf < 4; ++nf) {
      int r = wc * 64 + nf * 16 + lr;
      bfr[nf] = asbf(*(const u16x8*)(sB + r * 32 + ((lg ^ swz) * 8)));
    }
#pragma unroll
    for (int mf = 0; mf < 4; ++mf)
#pragma unroll
      for (int nf = 0; nf < 4; ++nf)
        acc[mf][nf] = __builtin_amdgcn_mfma_f32_16x16x32_bf16(af[mf], bfr[nf], acc[mf][nf], 0, 0, 0);
  }

  // epilogue: C/D layout col=lane&15, row=(lane>>4)*4+j  [m89/m91 verified]
#pragma unroll
  for (int nf = 0; nf < 4; ++nf) {
    const int col = n0 + wc * 64 + nf * 16 + lr;
    const float bcol = bias[col];
    if (EPI == 0) {
      const int which = col / 768;
      const int cm = col - which * 768;
      const int h = cm / 96;
      const int d = cm - h * 96;
      if (which < 2) {
        u16* qb = (u16*)outp + (size_t)which * QSEG;
#pragma unroll
        for (int mf = 0; mf < 4; ++mf)
#pragma unroll
          for (int j = 0; j < 4; ++j) {
            const int row = m0 + wr * 64 + mf * 16 + lg * 4 + j;
            const int b = row >> 11, tok = row & 2047;
            qb[((size_t)((b * NH + h) * SEQ + tok)) * HD + d] = f2bf(acc[mf][nf][j] + bcol);
          }
      } else {  // V -> V^T layout [pair][d][tok]
        u16* vbp = (u16*)outp + 2 * (size_t)QSEG;
#pragma unroll
        for (int mf = 0; mf < 4; ++mf)
#pragma unroll
          for (int j = 0; j < 4; ++j) {
            const int row = m0 + wr * 64 + mf * 16 + lg * 4 + j;
            const int b = row >> 11, tok = row & 2047;
            vbp[((size_t)((b * NH + h) * HD + d)) * SEQ + tok] = f2bf(acc[mf][nf][j] + bcol);
          }
      }
    } else {
#pragma unroll
      for (int mf = 0; mf < 4; ++mf)
#pragma unroll
        for (int j = 0; j < 4; ++j) {
          const int row = m0 + wr * 64 + mf * 16 + lg * 4 + j;
          const float v = acc[mf][nf][j] + bcol;
          const size_t off = (size_t)row * N + col;
          if (EPI == 1 || EPI == 3) {
            ((float*)outp)[off] = v + resid[off];
          } else {  // EPI == 2, exact GELU
            ((u16*)outp)[off] = f2bf(0.5f * v * (1.0f + erff(v * 0.70710678f)));
          }
        }
    }
  }
}

// ---------------------------------------------------------------------------
// Flash attention. qkv bf16: Q,K = [32 pairs][2048][96]; V = [32 pairs][96][2048] (V^T).
// Block = 4 waves; wave owns 16 Q rows (Q-tile 64); K-tile 64; 32 kt iters.
// V^T tile staged via global_load_lds with chunk-XOR swizzle (src + read side).
// softmax UNSCALED (faithful to ref); 1/sqrt(768) folded into final O.
// Output obuf: bf16 [b][tok][h*96+d] = [8192][768].
// ---------------------------------------------------------------------------
__global__ __launch_bounds__(256, 4)
void attn_k(const u16* __restrict__ qkv, u16* __restrict__ obuf) {
  __shared__ __align__(16) u16 sK[64 * 120];   // reg-staged, pad 120 (2-way free)
  __shared__ __align__(16) u16 sVt[96 * 64];   // gload-staged [d][k], chunk-swizzled
  __shared__ __align__(16) u16 sP[4][16 * 72]; // per-wave P[16][64], 72 stride
  // XCD chunk swizzle: each XCD owns 4 consecutive (b,h) pairs -> KV L2-local
  const int bidf = blockIdx.y * 32 + blockIdx.x;
  const int sw = (bidf & 7) * 128 + (bidf >> 3);
  const int p = sw >> 5;   // (b,h) pair
  const int qt = sw & 31;  // q tile
  const int t = threadIdx.x;
  const int w = t >> 6, l = t & 63;
  const int lr = l & 15, lg = l >> 4;
  const u16* qb = qkv + (size_t)p * SEQ * HD;
  const u16* kb = qb + QSEG;
  const u16* vtb = qkv + 2 * (size_t)QSEG + (size_t)p * SEQ * HD;  // [d][tok]
  const int q0 = qt * 64 + w * 16;

  // V^T staging map: chunk q=t+i*256 -> LDS slot (r=q>>3, c=q&7); data chunk = c^(r&7)
  const u16* vsrc[3];
  u16* vdst[3];
#pragma unroll
  for (int i = 0; i < 3; ++i) {
    const int q = t + i * 256;
    const int r = q >> 3, c = q & 7;
    vsrc[i] = vtb + (size_t)r * SEQ + ((c ^ (r & 7)) * 8);
    vdst[i] = sVt + q * 8;
  }
  const u16* ksrc = kb + (size_t)l * HD;

  bf16x8 aq[3];
#pragma unroll
  for (int kb3 = 0; kb3 < 3; ++kb3)
    aq[kb3] = asbf(*(const u16x8*)(qb + (size_t)(q0 + lr) * HD + kb3 * 32 + lg * 8));

  f32x4 accO[6] = {};
  float mrow[4] = {-1e30f, -1e30f, -1e30f, -1e30f};
  float lrow[4] = {0.f, 0.f, 0.f, 0.f};

  for (int kt = 0; kt < 32; ++kt) {
    __syncthreads();
#pragma unroll
    for (int i = 0; i < 3; ++i) gload16(vsrc[i] + kt * 64, vdst[i]);
    const u16* kbase = ksrc + (size_t)(kt * 64) * HD;
#pragma unroll
    for (int j = 0; j < 3; ++j) {
      const int c0 = (w + j * 4) * 8;
      *(u16x8*)(&sK[l * 120 + c0]) = *(const u16x8*)(kbase + c0);
    }
    __syncthreads();

    // S = Q @ K^T  (rows: lg*4+j, cols: nf*16+lr)
    f32x4 s4[4] = {};
#pragma unroll
    for (int nf = 0; nf < 4; ++nf)
#pragma unroll
      for (int kb3 = 0; kb3 < 3; ++kb3) {
        bf16x8 bk_ = asbf(*(const u16x8*)(&sK[(nf * 16 + lr) * 120 + kb3 * 32 + lg * 8]));
        s4[nf] = __builtin_amdgcn_mfma_f32_16x16x32_bf16(aq[kb3], bk_, s4[nf], 0, 0, 0);
      }

    // online softmax (row reductions across 16-lane groups)
    float tmax[4];
#pragma unroll
    for (int j = 0; j < 4; ++j) {
      tmax[j] = fmaxf(fmaxf(s4[0][j], s4[1][j]), fmaxf(s4[2][j], s4[3][j]));
#pragma unroll
      for (int m = 8; m; m >>= 1) tmax[j] = fmaxf(tmax[j], __shfl_xor(tmax[j], m, 64));
    }
    float alpha[4];
#pragma unroll
    for (int j = 0; j < 4; ++j) {
      const float mn = fmaxf(mrow[j], tmax[j]);
      alpha[j] = __expf(mrow[j] - mn);
      mrow[j] = mn;
    }
    float psum[4] = {0.f, 0.f, 0.f, 0.f};
#pragma unroll
    for (int nf = 0; nf < 4; ++nf)
#pragma unroll
      for (int j = 0; j < 4; ++j) {
        const float pv = __expf(s4[nf][j] - mrow[j]);
        psum[j] += pv;
        sP[w][(lg * 4 + j) * 72 + nf * 16 + lr] = f2bf(pv);
      }
#pragma unroll
    for (int j = 0; j < 4; ++j) {
#pragma unroll
      for (int m = 8; m; m >>= 1) psum[j] += __shfl_xor(psum[j], m, 64);
      lrow[j] = lrow[j] * alpha[j] + psum[j];
    }
#pragma unroll
    for (int nf2 = 0; nf2 < 6; ++nf2)
#pragma unroll
      for (int j = 0; j < 4; ++j) accO[nf2][j] *= alpha[j];

    asm volatile("s_waitcnt lgkmcnt(0)" ::: "memory");

    // O += P @ V  (A = P[16][64] from sP, B from swizzled sVt [d][k])
#pragma unroll
    for (int kf = 0; kf < 2; ++kf) {
      bf16x8 ap = asbf(*(const u16x8*)(&sP[w][lr * 72 + kf * 32 + lg * 8]));
#pragma unroll
      for (int nf2 = 0; nf2 < 6; ++nf2) {
        const int vr = nf2 * 16 + lr;
        const int cs = ((kf << 2) | lg) ^ (lr & 7);
        bf16x8 bv_ = asbf(*(const u16x8*)(&sVt[vr * 64 + cs * 8]));
        accO[nf2] = __builtin_amdgcn_mfma_f32_16x16x32_bf16(ap, bv_, accO[nf2], 0, 0, 0);
      }
    }
  }

  // epilogue: O / (l * sqrt(768)), scatter to [b][tok][h*96+d]
  const int b = p >> 3, h = p & 7;
  float sc[4];
#pragma unroll
  for (int j = 0; j < 4; ++j) sc[j] = 0.03608439182435161f / lrow[j];
#pragma unroll
  for (int nf2 = 0; nf2 < 6; ++nf2)
#pragma unroll
    for (int j = 0; j < 4; ++j) {
      const int tok = q0 + lg * 4 + j;
      obuf[(size_t)(b * SEQ + tok) * EMB + h * HD + nf2 * 16 + lr] = f2bf(accO[nf2][j] * sc[j]);
    }
}

// ---------------------------------------------------------------------------
extern "C" void kernel_launch(void* const* d_in, const int* in_sizes, int n_in,
                              void* d_out, int out_size, void* d_ws, size_t ws_size,
                              hipStream_t stream) {
  const float* x    = (const float*)d_in[0];
  const float* ln1g = (const float*)d_in[1];
  const float* ln1b = (const float*)d_in[2];
  const float* wq   = (const float*)d_in[3];
  const float* bq   = (const float*)d_in[4];
  const float* wk   = (const float*)d_in[5];
  const float* bk   = (const float*)d_in[6];
  const float* wv   = (const float*)d_in[7];
  const float* bv   = (const float*)d_in[8];
  const float* wo   = (const float*)d_in[9];
  const float* bo   = (const float*)d_in[10];
  const float* ln2g = (const float*)d_in[11];
  const float* ln2b = (const float*)d_in[12];
  const float* w1   = (const float*)d_in[13];
  const float* b1   = (const float*)d_in[14];
  const float* w2   = (const float*)d_in[15];
  const float* b2   = (const float*)d_in[16];
  float* out = (float*)d_out;

  char* ws = (char*)d_ws;
  u16* wqkvT  = (u16*)ws;   ws += (size_t)2304 * 768 * 2;
  u16* woT    = (u16*)ws;   ws += (size_t)768 * 768 * 2;
  u16* w1T    = (u16*)ws;   ws += (size_t)3072 * 768 * 2;
  u16* w2T    = (u16*)ws;   ws += (size_t)768 * 3072 * 2;
  float* bqkv = (float*)ws; ws += (size_t)2304 * 4;
  u16* bufA   = (u16*)ws;   ws += (size_t)NTOK * EMB * 2;   // y -> o -> z
  u16* bigbuf = (u16*)ws;   ws += (size_t)NTOK * DFF * 2;   // qkv -> ffn hidden
  float* x1   = (float*)ws; ws += (size_t)NTOK * EMB * 4;

  // weights -> bf16 B^T
  transpose_cvt<<<dim3(24, 24), 256, 0, stream>>>(wq, wqkvT, 768, 768);
  transpose_cvt<<<dim3(24, 24), 256, 0, stream>>>(wk, wqkvT + 768 * 768, 768, 768);
  transpose_cvt<<<dim3(24, 24), 256, 0, stream>>>(wv, wqkvT + 2 * 768 * 768, 768, 768);
  transpose_cvt<<<dim3(24, 24), 256, 0, stream>>>(wo, woT, 768, 768);
  transpose_cvt<<<dim3(96, 24), 256, 0, stream>>>(w1, w1T, 768, 3072);
  transpose_cvt<<<dim3(24, 96), 256, 0, stream>>>(w2, w2T, 3072, 768);
  concat_bias<<<9, 256, 0, stream>>>(bq, bk, bv, bqkv);

  // LN1 -> y (bf16)
  ln_k<<<NTOK / 4, 256, 0, stream>>>(x, ln1g, ln1b, bufA);
  // QKV projection, scatter to head layout (V transposed)
  gemm_k<0><<<64 * 18, 256, 0, stream>>>(bufA, wqkvT, bqkv, nullptr, bigbuf,
                                         NTOK, 2304, 768, 18);
  // attention -> o (bf16, token-major), reuses bufA
  attn_k<<<dim3(32, 32), 256, 0, stream>>>(bigbuf, bufA);
  // O projection + residual -> x1 (fp32)
  gemm_k<1><<<64 * 6, 256, 0, stream>>>(bufA, woT, bo, x, x1, NTOK, 768, 768, 6);
  // LN2 -> z (bf16)
  ln_k<<<NTOK / 4, 256, 0, stream>>>(x1, ln2g, ln2b, bufA);
  // FFN1 + GELU -> hidden (bf16)
  gemm_k<2><<<64 * 24, 256, 0, stream>>>(bufA, w1T, b1, nullptr, bigbuf,
                                         NTOK, 3072, 768, 24);
  // FFN2 + residual -> out (fp32)
  gemm_k<3><<<64 * 6, 256, 0, stream>>>(bigbuf, w2T, b2, x1, out, NTOK, 768, 3072, 6);
}

// Round 4
// 429.112 us; speedup vs baseline: 1.2126x; 1.1368x over previous
//
#include <hip/hip_runtime.h>
#include <math.h>

#define SEQ    2048
#define NBATCH 4
#define NTOK   8192
#define EMB    768
#define DFF    3072
#define NH     8
#define HD     96
#define QSEG   6291456   // 32 pairs * 2048 * 96

typedef float            f32x4  __attribute__((ext_vector_type(4)));
typedef float            f32x16 __attribute__((ext_vector_type(16)));
typedef __bf16           bf16x8 __attribute__((ext_vector_type(8)));
typedef unsigned short   u16;
typedef unsigned int     u32;
typedef int              i32x2  __attribute__((ext_vector_type(2)));
typedef u16              u16x8  __attribute__((ext_vector_type(8)));
typedef u16              u16x4  __attribute__((ext_vector_type(4)));

__device__ __forceinline__ u16 f2bf(float f) {
  union { float f; unsigned u; } v; v.f = f;
  unsigned r = v.u + 0x7FFFu + ((v.u >> 16) & 1u);
  return (u16)(r >> 16);
}
__device__ __forceinline__ bf16x8 asbf(u16x8 v) { return __builtin_bit_cast(bf16x8, v); }
__device__ __forceinline__ u32 pk2(float a, float b) {
  union { __bf16 h[2]; u32 w; } u; u.h[0] = (__bf16)a; u.h[1] = (__bf16)b; return u.w;
}

__device__ __forceinline__ void gload16(const void* g, void* l) {
  __builtin_amdgcn_global_load_lds((const __attribute__((address_space(1))) unsigned*)g,
                                   (__attribute__((address_space(3))) unsigned*)l, 16, 0, 0);
}

// ---------------------------------------------------------------------------
// Generic fp32 [R][C] -> bf16 transposed [C][R] (weights -> B^T bf16)
// ---------------------------------------------------------------------------
__global__ __launch_bounds__(256)
void transpose_cvt(const float* __restrict__ in, u16* __restrict__ out, int R, int C) {
  __shared__ float tile[32][33];
  const int c0 = blockIdx.x * 32, r0 = blockIdx.y * 32;
  const int tr = threadIdx.x >> 5, tc = threadIdx.x & 31;
#pragma unroll
  for (int i = 0; i < 4; ++i)
    tile[tr + 8 * i][tc] = in[(size_t)(r0 + tr + 8 * i) * C + c0 + tc];
  __syncthreads();
#pragma unroll
  for (int i = 0; i < 4; ++i)
    out[(size_t)(c0 + tr + 8 * i) * R + r0 + tc] = f2bf(tile[tc][tr + 8 * i]);
}

__global__ __launch_bounds__(256)
void concat_bias(const float* __restrict__ bq, const float* __restrict__ bk,
                 const float* __restrict__ bv, float* __restrict__ out) {
  int i = blockIdx.x * 256 + threadIdx.x;
  if (i < 2304) {
    const float* s = (i < 768) ? bq : ((i < 1536) ? bk : bv);
    out[i] = s[i % 768];
  }
}

// ---------------------------------------------------------------------------
// LayerNorm: fp32 [rows][768] -> bf16 [rows][768]; one wave per row
// ---------------------------------------------------------------------------
__global__ __launch_bounds__(256)
void ln_k(const float* __restrict__ x, const float* __restrict__ g,
          const float* __restrict__ b, u16* __restrict__ y) {
  const int row = blockIdx.x * 4 + (threadIdx.x >> 6);
  const int l = threadIdx.x & 63;
  const float* xr = x + (size_t)row * EMB;
  f32x4 v[3];
#pragma unroll
  for (int i = 0; i < 3; ++i) v[i] = *(const f32x4*)(xr + (l + 64 * i) * 4);
  float s = 0.f;
#pragma unroll
  for (int i = 0; i < 3; ++i)
#pragma unroll
    for (int j = 0; j < 4; ++j) s += v[i][j];
#pragma unroll
  for (int m = 32; m; m >>= 1) s += __shfl_xor(s, m, 64);
  const float mu = s * (1.0f / EMB);
  float q = 0.f;
#pragma unroll
  for (int i = 0; i < 3; ++i)
#pragma unroll
    for (int j = 0; j < 4; ++j) { float d = v[i][j] - mu; q += d * d; }
#pragma unroll
  for (int m = 32; m; m >>= 1) q += __shfl_xor(q, m, 64);
  const float rstd = rsqrtf(q * (1.0f / EMB) + 1e-5f);
#pragma unroll
  for (int i = 0; i < 3; ++i) {
    const int c0 = (l + 64 * i) * 4;
    f32x4 gv = *(const f32x4*)(g + c0);
    f32x4 bv = *(const f32x4*)(b + c0);
    u16x4 o;
#pragma unroll
    for (int j = 0; j < 4; ++j) o[j] = f2bf((v[i][j] - mu) * rstd * gv[j] + bv[j]);
    *(u16x4*)(y + (size_t)row * EMB + c0) = o;
  }
}

// ---------------------------------------------------------------------------
// GEMM: C[M][N] = A[M][K](bf16) @ B^T[N][K](bf16) + epilogue
// EPI 0: +bias, scatter bf16 to qkv layout (Q,K: [p][tok][d]; V: [p][d][tok])
// EPI 1: +bias +resid -> fp32
// EPI 2: +bias, exact GELU -> bf16
// EPI 3: +bias +resid -> fp32
// ---------------------------------------------------------------------------
template <int EPI>
__global__ __launch_bounds__(256, 3)
void gemm_k(const u16* __restrict__ A, const u16* __restrict__ BT,
            const float* __restrict__ bias, const float* __restrict__ resid,
            void* __restrict__ outp, int M, int N, int K, int nbn) {
  __shared__ __align__(16) u16 sA[128 * 32];
  __shared__ __align__(16) u16 sB[128 * 32];
  const int t = threadIdx.x;
  const int w = t >> 6, l = t & 63;
  const int wr = w >> 1, wc = w & 1;
  const int lr = l & 15, lg = l >> 4;
  const int cpx = gridDim.x >> 3;
  const int bid = (blockIdx.x & 7) * cpx + (blockIdx.x >> 3);
  const int bm = bid / nbn, bn = bid % nbn;
  const int m0 = bm << 7, n0 = bn << 7;

  const int r0 = t >> 2;
  const int cL = t & 3;
  const int cG0 = cL ^ ((r0 >> 1) & 3);
  const int cG1 = cL ^ (((r0 + 64) >> 1) & 3);
  const u16* gA0 = A + (size_t)(m0 + r0) * K + cG0 * 8;
  const u16* gA1 = A + (size_t)(m0 + r0 + 64) * K + cG1 * 8;
  const u16* gB0 = BT + (size_t)(n0 + r0) * K + cG0 * 8;
  const u16* gB1 = BT + (size_t)(n0 + r0 + 64) * K + cG1 * 8;
  u16* lA0 = sA + t * 8;
  u16* lA1 = sA + 2048 + t * 8;
  u16* lB0 = sB + t * 8;
  u16* lB1 = sB + 2048 + t * 8;

  f32x4 acc[4][4] = {};
  const int swz = (lr >> 1) & 3;

  for (int kt = 0; kt < K; kt += 32) {
    __syncthreads();
    gload16(gA0 + kt, lA0);
    gload16(gA1 + kt, lA1);
    gload16(gB0 + kt, lB0);
    gload16(gB1 + kt, lB1);
    __syncthreads();
    bf16x8 af[4], bfr[4];
#pragma unroll
    for (int mf = 0; mf < 4; ++mf) {
      int r = wr * 64 + mf * 16 + lr;
      af[mf] = asbf(*(const u16x8*)(sA + r * 32 + ((lg ^ swz) * 8)));
    }
#pragma unroll
    for (int nf = 0; nf < 4; ++nf) {
      int r = wc * 64 + nf * 16 + lr;
      bfr[nf] = asbf(*(const u16x8*)(sB + r * 32 + ((lg ^ swz) * 8)));
    }
#pragma unroll
    for (int mf = 0; mf < 4; ++mf)
#pragma unroll
      for (int nf = 0; nf < 4; ++nf)
        acc[mf][nf] = __builtin_amdgcn_mfma_f32_16x16x32_bf16(af[mf], bfr[nf], acc[mf][nf], 0, 0, 0);
  }

#pragma unroll
  for (int nf = 0; nf < 4; ++nf) {
    const int col = n0 + wc * 64 + nf * 16 + lr;
    const float bcol = bias[col];
    if (EPI == 0) {
      const int which = col / 768;
      const int cm = col - which * 768;
      const int h = cm / 96;
      const int d = cm - h * 96;
      if (which < 2) {
        u16* qb = (u16*)outp + (size_t)which * QSEG;
#pragma unroll
        for (int mf = 0; mf < 4; ++mf)
#pragma unroll
          for (int j = 0; j < 4; ++j) {
            const int row = m0 + wr * 64 + mf * 16 + lg * 4 + j;
            const int b = row >> 11, tok = row & 2047;
            qb[((size_t)((b * NH + h) * SEQ + tok)) * HD + d] = f2bf(acc[mf][nf][j] + bcol);
          }
      } else {  // V -> V^T layout [pair][d][tok]
        u16* vbp = (u16*)outp + 2 * (size_t)QSEG;
#pragma unroll
        for (int mf = 0; mf < 4; ++mf)
#pragma unroll
          for (int j = 0; j < 4; ++j) {
            const int row = m0 + wr * 64 + mf * 16 + lg * 4 + j;
            const int b = row >> 11, tok = row & 2047;
            vbp[((size_t)((b * NH + h) * HD + d)) * SEQ + tok] = f2bf(acc[mf][nf][j] + bcol);
          }
      }
    } else {
#pragma unroll
      for (int mf = 0; mf < 4; ++mf)
#pragma unroll
        for (int j = 0; j < 4; ++j) {
          const int row = m0 + wr * 64 + mf * 16 + lg * 4 + j;
          const float v = acc[mf][nf][j] + bcol;
          const size_t off = (size_t)row * N + col;
          if (EPI == 1 || EPI == 3) {
            ((float*)outp)[off] = v + resid[off];
          } else {
            ((u16*)outp)[off] = f2bf(0.5f * v * (1.0f + erff(v * 0.70710678f)));
          }
        }
    }
  }
}

// ---------------------------------------------------------------------------
// Flash attention, 8-warp swapped 32x32 structure (m214-style).
// Q,K = [32 pairs][2048][96] bf16; V = [32 pairs][96][2048] bf16 (V^T).
// Block = 8 warps x QBLK=32 q-rows (Q-tile 256); KVBLK=64; 32 kt iters.
// S^T = mfma_32x32x16(K, Q): each lane holds 32 scores of ONE q-row
// -> softmax fully in-register (31 fmax + 1 shfl + 32 exp, no LDS).
// P -> PV B-operand via bf16-pack + 2x permlane32_swap per k-step (T12).
// O^T = mfma_32x32x16(V^T, P^T). Defer-max rescale (T13, THR=8).
// K/V tiles double-buffered in LDS, staged by global_load_lds with
// chunk-XOR pre-swizzled global source (G21), min-2-phase pipeline.
// softmax UNSCALED (faithful to ref); 1/sqrt(768) folded into epilogue.
// ---------------------------------------------------------------------------
__global__ __launch_bounds__(512, 2)
void attn_k(const u16* __restrict__ qkv, u16* __restrict__ obuf) {
  __shared__ __align__(16) u16 sK[2][64 * 128];  // 64 rows x 16 chunks (12 real)
  __shared__ __align__(16) u16 sV[2][128 * 64];  // 128 rows (96 real) x 8 chunks
  const int bid = blockIdx.x;
  const int x = bid & 7, i = bid >> 3;           // XCD x owns pairs 4x..4x+3
  const int p = x * 4 + (i & 3), qt = i >> 2;
  const int t = threadIdx.x;
  const int w = t >> 6, l = t & 63;
  const int hl = l >> 5, lm = l & 31;
  const u16* qb  = qkv + (size_t)p * SEQ * HD;
  const u16* kb  = qb + QSEG;
  const u16* vtb = qkv + 2 * (size_t)QSEG + (size_t)p * SEQ * HD;
  const int q0w = qt * 256 + w * 32;

  // Q frags (B-operand: n=q=lm, k=d): held in registers whole kernel
  bf16x8 qf[6];
#pragma unroll
  for (int ds = 0; ds < 6; ++ds)
    qf[ds] = asbf(*(const u16x8*)(qb + (size_t)(q0w + lm) * HD + ds * 16 + hl * 8));

  // staging source offsets (pre-swizzled global, linear LDS dest)
  const int rK0 = t >> 4,        ccK0 = (t & 15) ^ (rK0 & 7);
  const int rK1 = 32 + (t >> 4), ccK1 = (t & 15) ^ (rK1 & 7);
  const int koff0 = rK0 * HD + ccK0 * 8;
  const int koff1 = rK1 * HD + ccK1 * 8;
  const int rV0 = t >> 3,        ccV0 = (t & 7) ^ (rV0 & 7);
  const int rV1 = 64 + (t >> 3), ccV1 = (t & 7) ^ (rV1 & 7);
  const int voff0 = rV0 * SEQ + ccV0 * 8;
  const int voff1 = rV1 * SEQ + ccV1 * 8;

#define ASTAGE(bi, kt_) {                                            \
    const u16* kbase = kb + (size_t)(kt_) * 64 * HD;                 \
    gload16(kbase + koff0, &sK[bi][t * 8]);                          \
    gload16(kbase + koff1, &sK[bi][4096 + t * 8]);                   \
    const u16* vbase = vtb + (kt_) * 64;                             \
    gload16(vbase + voff0, &sV[bi][t * 8]);                          \
    gload16(vbase + voff1, &sV[bi][4096 + t * 8]); }

  f32x16 oacc[3] = {};
  float mreg = -1e30f, lsum = 0.f;
  int cur = 0;

  ASTAGE(0, 0);
  for (int kt = 0; kt < 32; ++kt) {
    asm volatile("s_waitcnt vmcnt(0)" ::: "memory");
    __syncthreads();
    if (kt < 31) ASTAGE(cur ^ 1, kt + 1);

    // S^T = K @ Q  (lane: q=lm; rows kv = tile*32 + (r&3)+8*(r>>2)+4*hl)
    f32x16 st[2] = {};
#pragma unroll
    for (int tile = 0; tile < 2; ++tile)
#pragma unroll
      for (int ds = 0; ds < 6; ++ds) {
        const int row = tile * 32 + lm;
        const int cs = (2 * ds + hl) ^ (l & 7);
        bf16x8 kf = asbf(*(const u16x8*)(&sK[cur][row * 128 + cs * 8]));
        st[tile] = __builtin_amdgcn_mfma_f32_32x32x16_bf16(kf, qf[ds], st[tile], 0, 0, 0);
      }

    // in-register online softmax (row is lane-local + partner half)
    float pmax = st[0][0];
#pragma unroll
    for (int r = 1; r < 16; ++r) pmax = fmaxf(pmax, st[0][r]);
#pragma unroll
    for (int r = 0; r < 16; ++r) pmax = fmaxf(pmax, st[1][r]);
    pmax = fmaxf(pmax, __shfl_xor(pmax, 32, 64));
    if (__any(pmax > mreg + 8.f)) {   // defer-max (T13)
      const float mn = fmaxf(mreg, pmax);
      const float al = __expf(mreg - mn);
      mreg = mn; lsum *= al;
#pragma unroll
      for (int d3 = 0; d3 < 3; ++d3)
#pragma unroll
        for (int r = 0; r < 16; ++r) oacc[d3][r] *= al;
    }
    float ts = 0.f;
    u32 wds[16];
#pragma unroll
    for (int g = 0; g < 8; ++g) {
      const float e0 = __expf(st[(4 * g) >> 4][(4 * g) & 15] - mreg);
      const float e1 = __expf(st[(4 * g + 1) >> 4][(4 * g + 1) & 15] - mreg);
      const float e2 = __expf(st[(4 * g + 2) >> 4][(4 * g + 2) & 15] - mreg);
      const float e3 = __expf(st[(4 * g + 3) >> 4][(4 * g + 3) & 15] - mreg);
      ts += (e0 + e1) + (e2 + e3);
      wds[2 * g]     = pk2(e0, e1);
      wds[2 * g + 1] = pk2(e2, e3);
    }
    ts += __shfl_xor(ts, 32, 64);
    lsum += ts;

    // O^T += V^T @ P^T ; P B-frag for step s = p[8s..8s+7] via 2 swaps
#pragma unroll
    for (int s = 0; s < 4; ++s) {
      i32x2 r02 = __builtin_amdgcn_permlane32_swap((int)wds[4 * s], (int)wds[4 * s + 2], false, false);
      i32x2 r13 = __builtin_amdgcn_permlane32_swap((int)wds[4 * s + 1], (int)wds[4 * s + 3], false, false);
      union { u32 wu[4]; bf16x8 v; } pu;
      pu.wu[0] = (u32)r02[0]; pu.wu[1] = (u32)r13[0];
      pu.wu[2] = (u32)r02[1]; pu.wu[3] = (u32)r13[1];
      const bf16x8 pf = pu.v;
#pragma unroll
      for (int d3 = 0; d3 < 3; ++d3) {
        const int row = d3 * 32 + lm;
        const int cs = (2 * s + hl) ^ (l & 7);
        bf16x8 vf = asbf(*(const u16x8*)(&sV[cur][row * 64 + cs * 8]));
        oacc[d3] = __builtin_amdgcn_mfma_f32_32x32x16_bf16(vf, pf, oacc[d3], 0, 0, 0);
      }
    }
    cur ^= 1;
  }

  // epilogue: O^T[d][q] -> obuf[b][tok][h*96+d], scaled by 1/(lsum*sqrt(768))
  const int b = p >> 3, h = p & 7;
  const float sc = 0.03608439182435161f / lsum;
  u16* ob = obuf + (size_t)(b * SEQ + q0w + lm) * EMB + h * HD;
#pragma unroll
  for (int d3 = 0; d3 < 3; ++d3)
#pragma unroll
    for (int g = 0; g < 4; ++g) {
      u16x4 o4;
#pragma unroll
      for (int j = 0; j < 4; ++j) o4[j] = f2bf(oacc[d3][4 * g + j] * sc);
      *(u16x4*)(ob + d3 * 32 + 8 * g + 4 * hl) = o4;
    }
#undef ASTAGE
}

// ---------------------------------------------------------------------------
extern "C" void kernel_launch(void* const* d_in, const int* in_sizes, int n_in,
                              void* d_out, int out_size, void* d_ws, size_t ws_size,
                              hipStream_t stream) {
  const float* x    = (const float*)d_in[0];
  const float* ln1g = (const float*)d_in[1];
  const float* ln1b = (const float*)d_in[2];
  const float* wq   = (const float*)d_in[3];
  const float* bq   = (const float*)d_in[4];
  const float* wk   = (const float*)d_in[5];
  const float* bk   = (const float*)d_in[6];
  const float* wv   = (const float*)d_in[7];
  const float* bv   = (const float*)d_in[8];
  const float* wo   = (const float*)d_in[9];
  const float* bo   = (const float*)d_in[10];
  const float* ln2g = (const float*)d_in[11];
  const float* ln2b = (const float*)d_in[12];
  const float* w1   = (const float*)d_in[13];
  const float* b1   = (const float*)d_in[14];
  const float* w2   = (const float*)d_in[15];
  const float* b2   = (const float*)d_in[16];
  float* out = (float*)d_out;

  char* ws = (char*)d_ws;
  u16* wqkvT  = (u16*)ws;   ws += (size_t)2304 * 768 * 2;
  u16* woT    = (u16*)ws;   ws += (size_t)768 * 768 * 2;
  u16* w1T    = (u16*)ws;   ws += (size_t)3072 * 768 * 2;
  u16* w2T    = (u16*)ws;   ws += (size_t)768 * 3072 * 2;
  float* bqkv = (float*)ws; ws += (size_t)2304 * 4;
  u16* bufA   = (u16*)ws;   ws += (size_t)NTOK * EMB * 2;   // y -> o -> z
  u16* bigbuf = (u16*)ws;   ws += (size_t)NTOK * DFF * 2;   // qkv -> ffn hidden
  float* x1   = (float*)ws; ws += (size_t)NTOK * EMB * 4;

  transpose_cvt<<<dim3(24, 24), 256, 0, stream>>>(wq, wqkvT, 768, 768);
  transpose_cvt<<<dim3(24, 24), 256, 0, stream>>>(wk, wqkvT + 768 * 768, 768, 768);
  transpose_cvt<<<dim3(24, 24), 256, 0, stream>>>(wv, wqkvT + 2 * 768 * 768, 768, 768);
  transpose_cvt<<<dim3(24, 24), 256, 0, stream>>>(wo, woT, 768, 768);
  transpose_cvt<<<dim3(96, 24), 256, 0, stream>>>(w1, w1T, 768, 3072);
  transpose_cvt<<<dim3(24, 96), 256, 0, stream>>>(w2, w2T, 3072, 768);
  concat_bias<<<9, 256, 0, stream>>>(bq, bk, bv, bqkv);

  ln_k<<<NTOK / 4, 256, 0, stream>>>(x, ln1g, ln1b, bufA);
  gemm_k<0><<<64 * 18, 256, 0, stream>>>(bufA, wqkvT, bqkv, nullptr, bigbuf,
                                         NTOK, 2304, 768, 18);
  attn_k<<<256, 512, 0, stream>>>(bigbuf, bufA);
  gemm_k<1><<<64 * 6, 256, 0, stream>>>(bufA, woT, bo, x, x1, NTOK, 768, 768, 6);
  ln_k<<<NTOK / 4, 256, 0, stream>>>(x1, ln2g, ln2b, bufA);
  gemm_k<2><<<64 * 24, 256, 0, stream>>>(bufA, w1T, b1, nullptr, bigbuf,
                                         NTOK, 3072, 768, 24);
  gemm_k<3><<<64 * 6, 256, 0, stream>>>(bigbuf, w2T, b2, x1, out, NTOK, 768, 3072, 6);
}